// Round 2
// baseline (1937.945 us; speedup 1.0000x reference)
//
#include <hip/hip_runtime.h>
#include <hip/hip_bf16.h>

typedef __attribute__((ext_vector_type(8))) short short8;
typedef __attribute__((ext_vector_type(4))) float f32x4;

#define B_  4
#define M_  2048
#define K_  4096
#define N_  4096
#define MT  (B_ * M_)   // 8192 rows

#define BM  128
#define BN  128
#define BK  64
#define LDSB (BK * 2)   // 128 bytes per LDS row (bf16)

// fp32 -> bf16 round-to-nearest-even (finite inputs)
__device__ __forceinline__ unsigned short f2bf(float f) {
    unsigned u = __builtin_bit_cast(unsigned, f);
    unsigned r = (u + 0x7fffu + ((u >> 16) & 1u)) >> 16;
    return (unsigned short)r;
}

// XOR swizzle: kills 128B-stride bank conflicts on ds_read_b128 (G4)
__device__ __forceinline__ int swz(int row, int kbyte) {
    return row * LDSB + (kbyte ^ ((row & 7) << 4));
}

__global__ __launch_bounds__(256) void ternary_gemm(
    const float* __restrict__ x, const float* __restrict__ w,
    float* __restrict__ out)
{
    __shared__ __align__(16) char lds_a[BM * LDSB];  // [row m][k] bf16, swizzled
    __shared__ __align__(16) char lds_w[BN * LDSB];  // [col n][k] bf16 (transposed), swizzled

    const int tid  = threadIdx.x;
    const int bn   = blockIdx.x * BN;
    const int bm   = blockIdx.y * BM;

    const int wave = tid >> 6;
    const int lane = tid & 63;
    const int lr   = lane & 15;
    const int lg   = lane >> 4;
    const int wm   = (wave >> 1) * 64;  // wave's row offset in tile
    const int wn   = (wave & 1) * 64;   // wave's col offset in tile

    f32x4 acc[4][4];
    #pragma unroll
    for (int i = 0; i < 4; ++i)
        #pragma unroll
        for (int j = 0; j < 4; ++j)
            acc[i][j] = f32x4{0.f, 0.f, 0.f, 0.f};

    // staging coords
    const int ar  = tid >> 4;          // A: base row 0..15 (step 16)
    const int ak  = (tid & 15) * 4;    // A: k offset in floats
    const int wk  = tid >> 5;          // W: base k 0..7 (step 8)
    const int wn4 = (tid & 31) * 4;    // W: n offset in floats

    for (int k0 = 0; k0 < K_; k0 += BK) {
        // ---- stage A tile: 128 rows x 64 k (fp32 -> bf16) ----
        #pragma unroll
        for (int it = 0; it < 8; ++it) {
            const int row = ar + it * 16;
            const float4 v = *reinterpret_cast<const float4*>(
                &x[(size_t)(bm + row) * K_ + k0 + ak]);
            uint2 p;
            p.x = (unsigned)f2bf(v.x) | ((unsigned)f2bf(v.y) << 16);
            p.y = (unsigned)f2bf(v.z) | ((unsigned)f2bf(v.w) << 16);
            *reinterpret_cast<uint2*>(&lds_a[swz(row, ak * 2)]) = p;
        }
        // ---- stage W tile TRANSPOSED: lds_w[n][k] (fp32 -> bf16) ----
        #pragma unroll
        for (int it = 0; it < 8; ++it) {
            const int kk = wk + it * 8;
            const float4 v = *reinterpret_cast<const float4*>(
                &w[(size_t)(k0 + kk) * N_ + bn + wn4]);
            unsigned short h0 = f2bf(v.x), h1 = f2bf(v.y), h2 = f2bf(v.z), h3 = f2bf(v.w);
            *reinterpret_cast<unsigned short*>(&lds_w[swz(wn4 + 0, kk * 2)]) = h0;
            *reinterpret_cast<unsigned short*>(&lds_w[swz(wn4 + 1, kk * 2)]) = h1;
            *reinterpret_cast<unsigned short*>(&lds_w[swz(wn4 + 2, kk * 2)]) = h2;
            *reinterpret_cast<unsigned short*>(&lds_w[swz(wn4 + 3, kk * 2)]) = h3;
        }
        __syncthreads();

        // ---- MFMA: 2 k-steps of 32, 4x4 fragments per wave ----
        #pragma unroll
        for (int ks = 0; ks < 2; ++ks) {
            const int kb = ks * 64 + lg * 16;  // byte offset of this lane's 8-elem k-group
            short8 a[4], b[4];
            #pragma unroll
            for (int mi = 0; mi < 4; ++mi)
                a[mi] = *reinterpret_cast<const short8*>(&lds_a[swz(wm + mi * 16 + lr, kb)]);
            #pragma unroll
            for (int ni = 0; ni < 4; ++ni)
                b[ni] = *reinterpret_cast<const short8*>(&lds_w[swz(wn + ni * 16 + lr, kb)]);
            #pragma unroll
            for (int mi = 0; mi < 4; ++mi)
                #pragma unroll
                for (int ni = 0; ni < 4; ++ni)
                    acc[mi][ni] = __builtin_amdgcn_mfma_f32_16x16x32_bf16(
                        a[mi], b[ni], acc[mi][ni], 0, 0, 0);
        }
        __syncthreads();
    }

    // ---- epilogue: C/D layout col=lane&15, row=(lane>>4)*4+r ----
    #pragma unroll
    for (int mi = 0; mi < 4; ++mi) {
        #pragma unroll
        for (int ni = 0; ni < 4; ++ni) {
            #pragma unroll
            for (int r = 0; r < 4; ++r) {
                const int row = bm + wm + mi * 16 + lg * 4 + r;
                const int col = bn + wn + ni * 16 + lr;
                out[(size_t)row * N_ + col] = acc[mi][ni][r];
            }
        }
    }
}

extern "C" void kernel_launch(void* const* d_in, const int* in_sizes, int n_in,
                              void* d_out, int out_size, void* d_ws, size_t ws_size,
                              hipStream_t stream) {
    const float* x = (const float*)d_in[0];
    const float* w = (const float*)d_in[1];
    float* out = (float*)d_out;

    dim3 grid(N_ / BN, MT / BM);  // 32 x 64 = 2048 blocks
    dim3 block(256);
    hipLaunchKernelGGL(ternary_gemm, grid, block, 0, stream, x, w, out);
}

// Round 3
// 645.064 us; speedup vs baseline: 3.0043x; 3.0043x over previous
//
#include <hip/hip_runtime.h>
#include <hip/hip_bf16.h>
#include <stdint.h>

typedef __attribute__((ext_vector_type(8))) short short8;
typedef __attribute__((ext_vector_type(4))) float f32x4;

#define B_  4
#define M_  2048
#define K_  4096
#define N_  4096
#define MT  (B_ * M_)   // 8192 rows

// fp32 -> bf16 round-to-nearest-even (finite inputs)
__device__ __forceinline__ unsigned f2bf(float f) {
    unsigned u = __builtin_bit_cast(unsigned, f);
    return (u + 0x7fffu + ((u >> 16) & 1u)) >> 16;
}

__device__ __forceinline__ void gload_lds16(const void* g, void* l) {
    __builtin_amdgcn_global_load_lds(
        (const __attribute__((address_space(1))) unsigned int*)g,
        (__attribute__((address_space(3))) unsigned int*)l,
        16 /*bytes, literal*/, 0, 0);
}

// ---------------- kernel 1: X fp32 -> bf16 (row-major, unchanged layout) ----
__global__ __launch_bounds__(256) void cvt_x(const float* __restrict__ x,
                                             unsigned short* __restrict__ xb) {
    const size_t n8 = (size_t)MT * K_ / 8;   // 16B-chunks of output
    for (size_t i = (size_t)blockIdx.x * 256 + threadIdx.x; i < n8;
         i += (size_t)gridDim.x * 256) {
        const float4 v0 = reinterpret_cast<const float4*>(x)[i * 2 + 0];
        const float4 v1 = reinterpret_cast<const float4*>(x)[i * 2 + 1];
        uint4 p;
        p.x = f2bf(v0.x) | (f2bf(v0.y) << 16);
        p.y = f2bf(v0.z) | (f2bf(v0.w) << 16);
        p.z = f2bf(v1.x) | (f2bf(v1.y) << 16);
        p.w = f2bf(v1.z) | (f2bf(v1.w) << 16);
        reinterpret_cast<uint4*>(xb)[i] = p;
    }
}

// ---------------- kernel 2: W [K][N] fp32 -> Wt [N][K] bf16 (transpose) -----
#define TS  64
#define TST 80   // LDS row stride in bf16 elems (160B: 16B-aligned, banks spread)
__global__ __launch_bounds__(256) void cvt_wt(const float* __restrict__ w,
                                              unsigned short* __restrict__ wt) {
    __shared__ unsigned short lt[TS * TST];  // [n_local][k_local]
    const int k0 = blockIdx.x * TS;
    const int n0 = blockIdx.y * TS;
    const int t  = threadIdx.x;
    const int c4 = t & 15;   // float4 column within 64-wide n
    const int r0 = t >> 4;   // k-row 0..15
    #pragma unroll
    for (int it = 0; it < 4; ++it) {
        const int r = r0 + it * 16;
        const float4 v = *reinterpret_cast<const float4*>(
            &w[(size_t)(k0 + r) * N_ + n0 + c4 * 4]);
        lt[(c4 * 4 + 0) * TST + r] = (unsigned short)f2bf(v.x);
        lt[(c4 * 4 + 1) * TST + r] = (unsigned short)f2bf(v.y);
        lt[(c4 * 4 + 2) * TST + r] = (unsigned short)f2bf(v.z);
        lt[(c4 * 4 + 3) * TST + r] = (unsigned short)f2bf(v.w);
    }
    __syncthreads();
    // write out 64 n-rows x 128B, 512 x 16B chunks, coalesced
    #pragma unroll
    for (int it = 0; it < 2; ++it) {
        const int idx = t + it * 256;
        const int nl = idx >> 3, ch = idx & 7;
        const uint4 val = *reinterpret_cast<const uint4*>(&lt[nl * TST + ch * 8]);
        *reinterpret_cast<uint4*>(&wt[(size_t)(n0 + nl) * K_ + k0 + ch * 8]) = val;
    }
}

// ---------------- kernel 3: bf16 MFMA GEMM, m97 structure ------------------
#define BM  128
#define BN  128
#define BK  64
#define LDA (BK * 2)   // 128 B per LDS row (linear — global_load_lds needs it)

__global__ __launch_bounds__(256) void gemm_bf16(
    const unsigned short* __restrict__ xb,   // [MT][K] bf16
    const unsigned short* __restrict__ wt,   // [N][K]  bf16
    float* __restrict__ out)
{
    __shared__ __align__(16) unsigned char la[BM * LDA];  // 16 KB
    __shared__ __align__(16) unsigned char lb[BN * LDA];  // 16 KB

    const int tid  = threadIdx.x;
    const int wave = tid >> 6, lane = tid & 63;
    const int lr = lane & 15, lg = lane >> 4;
    const int wm = (wave >> 1) * 64, wn = (wave & 1) * 64;
    const int bn = blockIdx.x * BN, bm = blockIdx.y * BM;

    f32x4 acc[4][4];
    #pragma unroll
    for (int i = 0; i < 4; ++i)
        #pragma unroll
        for (int j = 0; j < 4; ++j)
            acc[i][j] = f32x4{0.f, 0.f, 0.f, 0.f};

    // staging geometry: per wave, 4 x (1KB = 8 rows) per operand
    const int srow = wave * 32 + (lane >> 3);  // + i*8
    const int scol = (lane & 7) * 8;           // bf16 elems (16B chunk)
    const size_t a_base = (size_t)(bm + srow) * K_ + scol;
    const size_t b_base = (size_t)(bn + srow) * K_ + scol;
    unsigned char* const la_w = la + (size_t)wave * 4096;
    unsigned char* const lb_w = lb + (size_t)wave * 4096;

    for (int k0 = 0; k0 < K_; k0 += BK) {
        #pragma unroll
        for (int i = 0; i < 4; ++i)
            gload_lds16(xb + a_base + (size_t)i * 8 * K_ + k0, la_w + i * 1024);
        #pragma unroll
        for (int i = 0; i < 4; ++i)
            gload_lds16(wt + b_base + (size_t)i * 8 * K_ + k0, lb_w + i * 1024);
        __syncthreads();   // compiler drains vmcnt+lgkmcnt before s_barrier

        #pragma unroll
        for (int ks = 0; ks < 2; ++ks) {
            const int kb = ks * 64 + lg * 16;
            short8 a[4], b[4];
            #pragma unroll
            for (int mi = 0; mi < 4; ++mi)
                a[mi] = *reinterpret_cast<const short8*>(&la[(wm + mi * 16 + lr) * LDA + kb]);
            #pragma unroll
            for (int ni = 0; ni < 4; ++ni)
                b[ni] = *reinterpret_cast<const short8*>(&lb[(wn + ni * 16 + lr) * LDA + kb]);
            #pragma unroll
            for (int mi = 0; mi < 4; ++mi)
                #pragma unroll
                for (int ni = 0; ni < 4; ++ni)
                    acc[mi][ni] = __builtin_amdgcn_mfma_f32_16x16x32_bf16(
                        a[mi], b[ni], acc[mi][ni], 0, 0, 0);
        }
        __syncthreads();
    }

    // epilogue: C/D layout col=lane&15, row=(lane>>4)*4+r (verified round 2)
    #pragma unroll
    for (int mi = 0; mi < 4; ++mi)
        #pragma unroll
        for (int ni = 0; ni < 4; ++ni)
            #pragma unroll
            for (int r = 0; r < 4; ++r) {
                const int row = bm + wm + mi * 16 + lg * 4 + r;
                const int col = bn + wn + ni * 16 + lr;
                out[(size_t)row * N_ + col] = acc[mi][ni][r];
            }
}

// ---------------- fallback: round-2 fused kernel (passes, 1.8 ms) ----------
#define FLDSB (BK * 2)
__device__ __forceinline__ int fswz(int row, int kbyte) {
    return row * FLDSB + (kbyte ^ ((row & 7) << 4));
}
__global__ __launch_bounds__(256) void ternary_gemm_fused(
    const float* __restrict__ x, const float* __restrict__ w,
    float* __restrict__ out)
{
    __shared__ __align__(16) char lds_a[BM * FLDSB];
    __shared__ __align__(16) char lds_w[BN * FLDSB];
    const int tid = threadIdx.x;
    const int bn = blockIdx.x * BN, bm = blockIdx.y * BM;
    const int wave = tid >> 6, lane = tid & 63;
    const int lr = lane & 15, lg = lane >> 4;
    const int wm = (wave >> 1) * 64, wn = (wave & 1) * 64;
    f32x4 acc[4][4];
    #pragma unroll
    for (int i = 0; i < 4; ++i)
        #pragma unroll
        for (int j = 0; j < 4; ++j) acc[i][j] = f32x4{0.f, 0.f, 0.f, 0.f};
    const int ar = tid >> 4, ak = (tid & 15) * 4;
    const int wk = tid >> 5, wn4 = (tid & 31) * 4;
    for (int k0 = 0; k0 < K_; k0 += BK) {
        #pragma unroll
        for (int it = 0; it < 8; ++it) {
            const int row = ar + it * 16;
            const float4 v = *reinterpret_cast<const float4*>(
                &x[(size_t)(bm + row) * K_ + k0 + ak]);
            uint2 p;
            p.x = f2bf(v.x) | (f2bf(v.y) << 16);
            p.y = f2bf(v.z) | (f2bf(v.w) << 16);
            *reinterpret_cast<uint2*>(&lds_a[fswz(row, ak * 2)]) = p;
        }
        #pragma unroll
        for (int it = 0; it < 8; ++it) {
            const int kk = wk + it * 8;
            const float4 v = *reinterpret_cast<const float4*>(
                &w[(size_t)(k0 + kk) * N_ + bn + wn4]);
            *reinterpret_cast<unsigned short*>(&lds_w[fswz(wn4 + 0, kk * 2)]) = (unsigned short)f2bf(v.x);
            *reinterpret_cast<unsigned short*>(&lds_w[fswz(wn4 + 1, kk * 2)]) = (unsigned short)f2bf(v.y);
            *reinterpret_cast<unsigned short*>(&lds_w[fswz(wn4 + 2, kk * 2)]) = (unsigned short)f2bf(v.z);
            *reinterpret_cast<unsigned short*>(&lds_w[fswz(wn4 + 3, kk * 2)]) = (unsigned short)f2bf(v.w);
        }
        __syncthreads();
        #pragma unroll
        for (int ks = 0; ks < 2; ++ks) {
            const int kb = ks * 64 + lg * 16;
            short8 a[4], b[4];
            #pragma unroll
            for (int mi = 0; mi < 4; ++mi)
                a[mi] = *reinterpret_cast<const short8*>(&lds_a[fswz(wm + mi * 16 + lr, kb)]);
            #pragma unroll
            for (int ni = 0; ni < 4; ++ni)
                b[ni] = *reinterpret_cast<const short8*>(&lds_w[fswz(wn + ni * 16 + lr, kb)]);
            #pragma unroll
            for (int mi = 0; mi < 4; ++mi)
                #pragma unroll
                for (int ni = 0; ni < 4; ++ni)
                    acc[mi][ni] = __builtin_amdgcn_mfma_f32_16x16x32_bf16(
                        a[mi], b[ni], acc[mi][ni], 0, 0, 0);
        }
        __syncthreads();
    }
    #pragma unroll
    for (int mi = 0; mi < 4; ++mi)
        #pragma unroll
        for (int ni = 0; ni < 4; ++ni)
            #pragma unroll
            for (int r = 0; r < 4; ++r) {
                const int row = bm + wm + mi * 16 + lg * 4 + r;
                const int col = bn + wn + ni * 16 + lr;
                out[(size_t)row * N_ + col] = acc[mi][ni][r];
            }
}

extern "C" void kernel_launch(void* const* d_in, const int* in_sizes, int n_in,
                              void* d_out, int out_size, void* d_ws, size_t ws_size,
                              hipStream_t stream) {
    const float* x = (const float*)d_in[0];
    const float* w = (const float*)d_in[1];
    float* out = (float*)d_out;

    const size_t need = ((size_t)MT * K_ + (size_t)K_ * N_) * sizeof(unsigned short); // 96 MB
    if (ws_size >= need) {
        unsigned short* xb = (unsigned short*)d_ws;            // [MT][K] bf16
        unsigned short* wt = xb + (size_t)MT * K_;             // [N][K]  bf16
        hipLaunchKernelGGL(cvt_x, dim3(4096), dim3(256), 0, stream, x, xb);
        hipLaunchKernelGGL(cvt_wt, dim3(K_ / TS, N_ / TS), dim3(256), 0, stream, w, wt);
        hipLaunchKernelGGL(gemm_bf16, dim3(N_ / BN, MT / BM), dim3(256), 0, stream,
                           xb, wt, out);
    } else {
        hipLaunchKernelGGL(ternary_gemm_fused, dim3(N_ / BN, MT / BM), dim3(256), 0,
                           stream, x, w, out);
    }
}

// Round 4
// 473.808 us; speedup vs baseline: 4.0901x; 1.3614x over previous
//
#include <hip/hip_runtime.h>
#include <hip/hip_bf16.h>
#include <stdint.h>

typedef __attribute__((ext_vector_type(8))) short short8;
typedef __attribute__((ext_vector_type(4))) float f32x4;

#define B_  4
#define M_  2048
#define K_  4096
#define N_  4096
#define MT  (B_ * M_)   // 8192 rows

// fp32 -> bf16 round-to-nearest-even (finite inputs)
__device__ __forceinline__ unsigned f2bf(float f) {
    unsigned u = __builtin_bit_cast(unsigned, f);
    return (u + 0x7fffu + ((u >> 16) & 1u)) >> 16;
}

__device__ __forceinline__ void gload16(const void* g, void* l) {
    __builtin_amdgcn_global_load_lds(
        (const __attribute__((address_space(1))) unsigned int*)g,
        (__attribute__((address_space(3))) unsigned int*)l,
        16 /*bytes, literal*/, 0, 0);
}

// ---------------- kernel 1: X fp32 -> bf16 (row-major) ---------------------
__global__ __launch_bounds__(256) void cvt_x(const float* __restrict__ x,
                                             unsigned short* __restrict__ xb) {
    const size_t n8 = (size_t)MT * K_ / 8;
    for (size_t i = (size_t)blockIdx.x * 256 + threadIdx.x; i < n8;
         i += (size_t)gridDim.x * 256) {
        const float4 v0 = reinterpret_cast<const float4*>(x)[i * 2 + 0];
        const float4 v1 = reinterpret_cast<const float4*>(x)[i * 2 + 1];
        uint4 p;
        p.x = f2bf(v0.x) | (f2bf(v0.y) << 16);
        p.y = f2bf(v0.z) | (f2bf(v0.w) << 16);
        p.z = f2bf(v1.x) | (f2bf(v1.y) << 16);
        p.w = f2bf(v1.z) | (f2bf(v1.w) << 16);
        reinterpret_cast<uint4*>(xb)[i] = p;
    }
}

// ---------------- kernel 2: W [K][N] fp32 -> Wt [N][K] bf16 ----------------
#define TS  64
#define TST 80
__global__ __launch_bounds__(256) void cvt_wt(const float* __restrict__ w,
                                              unsigned short* __restrict__ wt) {
    __shared__ unsigned short lt[TS * TST];
    const int k0 = blockIdx.x * TS;
    const int n0 = blockIdx.y * TS;
    const int t  = threadIdx.x;
    const int c4 = t & 15;
    const int r0 = t >> 4;
    #pragma unroll
    for (int it = 0; it < 4; ++it) {
        const int r = r0 + it * 16;
        const float4 v = *reinterpret_cast<const float4*>(
            &w[(size_t)(k0 + r) * N_ + n0 + c4 * 4]);
        lt[(c4 * 4 + 0) * TST + r] = (unsigned short)f2bf(v.x);
        lt[(c4 * 4 + 1) * TST + r] = (unsigned short)f2bf(v.y);
        lt[(c4 * 4 + 2) * TST + r] = (unsigned short)f2bf(v.z);
        lt[(c4 * 4 + 3) * TST + r] = (unsigned short)f2bf(v.w);
    }
    __syncthreads();
    #pragma unroll
    for (int it = 0; it < 2; ++it) {
        const int idx = t + it * 256;
        const int nl = idx >> 3, ch = idx & 7;
        const uint4 val = *reinterpret_cast<const uint4*>(&lt[nl * TST + ch * 8]);
        *reinterpret_cast<uint4*>(&wt[(size_t)(n0 + nl) * K_ + k0 + ch * 8]) = val;
    }
}

// ---------------- kernel 3: 256x256 8-phase bf16 MFMA GEMM -----------------
// Geometry: BM=BN=256, BK=64, 8 waves (2Mx4N), per-wave out 128x64.
// LDS 128 KiB: 2 dbuf x (A0,A1,B0,B1 half-tiles of 16 KB).
// Chunk swizzle (T2): within each 1 KB subtile (16 rows x 32 bf16),
// physical_chunk = logical_chunk ^ (((chunk>>5)&1)<<1)  [row-bit3 XOR chunk-bit1]
// applied on BOTH the global source (pre-swizzle) and the ds_read address.
#define BK    64
#define NTIL  (K_ / BK)   // 64 k-tiles
#define HALF  16384
#define BUFSZ 65536

__global__ __launch_bounds__(512, 2) void gemm8(
    const unsigned short* __restrict__ xb,   // [MT][K] bf16
    const unsigned short* __restrict__ wt,   // [N][K]  bf16
    float* __restrict__ out)
{
    __shared__ __align__(16) char lds[2 * BUFSZ];   // 128 KiB

    const int tid  = threadIdx.x;
    const int w    = tid >> 6;
    const int lane = tid & 63;
    const int lr   = lane & 15;
    const int lg   = lane >> 4;
    const int wm_idx = w >> 2;        // 0..1  (M)
    const int wn_idx = w & 3;         // 0..3  (N)

    // XCD-aware bijective swizzle (nwg=512, 512%8==0)
    const int bid = blockIdx.x;
    const int swz = (bid & 7) * 64 + (bid >> 3);
    const int bm  = (swz >> 4) * 256;
    const int bn  = (swz & 15) * 256;

    // ---- staging source precompute (write-side inverse swizzle) ----
    // L = w*64 + lane (instr j adds 512): s=L>>6, cp=L&63,
    // c = cp ^ (((cp>>5)&1)<<1), r = (s>>1)*16 + (c>>2), koff = (s&1)*32 + (c&3)*8
    const int L   = w * 64 + lane;
    const int s0_ = L >> 6;
    const int cp  = L & 63;
    const int cl  = cp ^ (((cp >> 5) & 1) << 1);
    const int rst0 = (s0_ >> 1) * 16 + (cl >> 2);
    const int kst  = (s0_ & 1) * 32 + (cl & 3) * 8;
    // instr j=1: L+=512 -> row += 64, koff same
    const unsigned short* aS0 = xb + (size_t)(bm + rst0) * K_ + kst;
    const unsigned short* aS1 = xb + (size_t)(bm + rst0 + 64) * K_ + kst;
    const unsigned short* bS0 = wt + (size_t)(bn + rst0) * K_ + kst;
    const unsigned short* bS1 = wt + (size_t)(bn + rst0 + 64) * K_ + kst;
    char* const ldsw = lds + w * 1024;

    // ---- fragment read bases (read-side swizzle) ----
    const int laneoff = ((lr * 4 + lg) ^ (((lr >> 3) & 1) << 1)) * 16;
    const char* lpA = lds + wm_idx * HALF + laneoff;
    const char* lpB = lds + (2 + (wn_idx >> 1)) * HALF + (wn_idx & 1) * 8192 + laneoff;

    short8 af[4][2];   // one mi-half (4 mi x 2 ks), bank-reused
    short8 bf[4][2];   // all 4 ni x 2 ks
    f32x4  acc[8][4];
    #pragma unroll
    for (int i = 0; i < 8; ++i)
        #pragma unroll
        for (int j = 0; j < 4; ++j)
            acc[i][j] = f32x4{0.f, 0.f, 0.f, 0.f};

#define STAGE(ISB, HF, BUF, T) do {                                         \
        const size_t _k = (size_t)(((T) * BK) & (K_ - 1))                   \
                        + (size_t)(HF) * 128 * K_;                          \
        const unsigned short* _s0 = ((ISB) ? bS0 : aS0) + _k;               \
        const unsigned short* _s1 = ((ISB) ? bS1 : aS1) + _k;               \
        char* _l = ldsw + (BUF) * BUFSZ + ((ISB) * 2 + (HF)) * HALF;        \
        gload16(_s0, _l);                                                   \
        gload16(_s1, _l + 8192);                                            \
    } while (0)

#define LDA(H, BUF)                                                         \
    _Pragma("unroll") for (int m = 0; m < 4; ++m)                           \
    _Pragma("unroll") for (int ks = 0; ks < 2; ++ks)                        \
        af[m][ks] = *reinterpret_cast<const short8*>(                       \
            lpA + (BUF) * BUFSZ + (((H) * 4 + m) * 2 + ks) * 1024);

#define LDB(P, BUF)                                                         \
    _Pragma("unroll") for (int n = 0; n < 2; ++n)                           \
    _Pragma("unroll") for (int ks = 0; ks < 2; ++ks)                        \
        bf[(P) * 2 + n][ks] = *reinterpret_cast<const short8*>(             \
            lpB + (BUF) * BUFSZ + (((P) * 2 + n) * 2 + ks) * 1024);

#define MFMAQ(H, NLO)                                                       \
    __builtin_amdgcn_s_setprio(1);                                          \
    _Pragma("unroll") for (int m = 0; m < 4; ++m)                           \
    _Pragma("unroll") for (int n = 0; n < 2; ++n)                           \
    _Pragma("unroll") for (int ks = 0; ks < 2; ++ks)                        \
        acc[(H) * 4 + m][(NLO) + n] = __builtin_amdgcn_mfma_f32_16x16x32_bf16( \
            af[m][ks], bf[(NLO) + n][ks], acc[(H) * 4 + m][(NLO) + n], 0, 0, 0); \
    __builtin_amdgcn_s_setprio(0);

#define BAR() __builtin_amdgcn_s_barrier()

    // ---- prologue: tile0 (all 4 halves) -> buf0; tile1 A0,A1 -> buf1 ----
    STAGE(0, 0, 0, 0); STAGE(0, 1, 0, 0);
    STAGE(1, 0, 0, 0); STAGE(1, 1, 0, 0);
    STAGE(0, 0, 1, 1); STAGE(0, 1, 1, 1);
    asm volatile("s_waitcnt vmcnt(4)" ::: "memory");
    BAR();

    // ---- main loop: 8 phases per iter, 2 k-tiles per iter ----
    // slot map (iter computes T at ph1-4 from buf0, T+1 at ph5-8 from buf1):
    //   ph1: B0(T+1)->buf1  ph2: B1(T+1)->buf1  ph3: A0(T+2)->buf0  ph4: A1(T+2)->buf0 +vmcnt(4)
    //   ph5: B0(T+2)->buf0  ph6: B1(T+2)->buf0  ph7: A0(T+3)->buf1  ph8: A1(T+3)->buf1 +vmcnt(4)
#define HALFITER(BUF, TB, TA)                                               \
    /* q0 */ LDA(0, BUF); LDB(0, BUF);                                      \
    STAGE(1, 0, (BUF) ^ 1, TB);                                             \
    BAR(); MFMAQ(0, 0); BAR();                                              \
    /* q1 */ LDB(1, BUF);                                                   \
    STAGE(1, 1, (BUF) ^ 1, TB);                                             \
    BAR(); MFMAQ(0, 2); BAR();                                              \
    /* q2 */ LDA(1, BUF);                                                   \
    STAGE(0, 0, BUF, TA);                                                   \
    BAR(); MFMAQ(1, 0); BAR();                                              \
    /* q3 */ STAGE(0, 1, BUF, TA);                                          \
    asm volatile("s_waitcnt vmcnt(4)" ::: "memory");                        \
    BAR(); MFMAQ(1, 2); BAR();

    for (int i = 0; i < NTIL / 2; ++i) {
        const int T = 2 * i;
        HALFITER(0, T + 1, T + 2)
        HALFITER(1, T + 2, T + 3)
    }

    // ---- epilogue: C/D layout col=lane&15, row=(lane>>4)*4+r ----
    #pragma unroll
    for (int m = 0; m < 8; ++m)
        #pragma unroll
        for (int n = 0; n < 4; ++n)
            #pragma unroll
            for (int r = 0; r < 4; ++r) {
                const int row = bm + wm_idx * 128 + m * 16 + lg * 4 + r;
                const int col = bn + wn_idx * 64 + n * 16 + lr;
                out[(size_t)row * N_ + col] = acc[m][n][r];
            }
#undef STAGE
#undef LDA
#undef LDB
#undef MFMAQ
#undef BAR
#undef HALFITER
}

// ---------------- fallback: round-2 fused kernel (passes, 1.8 ms) ----------
#define BM  128
#define BN  128
#define FLDSB (BK * 2)
__device__ __forceinline__ int fswz(int row, int kbyte) {
    return row * FLDSB + (kbyte ^ ((row & 7) << 4));
}
__global__ __launch_bounds__(256) void ternary_gemm_fused(
    const float* __restrict__ x, const float* __restrict__ w,
    float* __restrict__ out)
{
    __shared__ __align__(16) char lds_a[BM * FLDSB];
    __shared__ __align__(16) char lds_w[BN * FLDSB];
    const int tid = threadIdx.x;
    const int bn = blockIdx.x * BN, bm = blockIdx.y * BM;
    const int wave = tid >> 6, lane = tid & 63;
    const int lr = lane & 15, lg = lane >> 4;
    const int wm = (wave >> 1) * 64, wn = (wave & 1) * 64;
    f32x4 acc[4][4];
    #pragma unroll
    for (int i = 0; i < 4; ++i)
        #pragma unroll
        for (int j = 0; j < 4; ++j) acc[i][j] = f32x4{0.f, 0.f, 0.f, 0.f};
    const int ar = tid >> 4, ak = (tid & 15) * 4;
    const int wk = tid >> 5, wn4 = (tid & 31) * 4;
    for (int k0 = 0; k0 < K_; k0 += BK) {
        #pragma unroll
        for (int it = 0; it < 8; ++it) {
            const int row = ar + it * 16;
            const float4 v = *reinterpret_cast<const float4*>(
                &x[(size_t)(bm + row) * K_ + k0 + ak]);
            uint2 p;
            p.x = f2bf(v.x) | (f2bf(v.y) << 16);
            p.y = f2bf(v.z) | (f2bf(v.w) << 16);
            *reinterpret_cast<uint2*>(&lds_a[fswz(row, ak * 2)]) = p;
        }
        #pragma unroll
        for (int it = 0; it < 8; ++it) {
            const int kk = wk + it * 8;
            const float4 v = *reinterpret_cast<const float4*>(
                &w[(size_t)(k0 + kk) * N_ + bn + wn4]);
            *reinterpret_cast<unsigned short*>(&lds_w[fswz(wn4 + 0, kk * 2)]) = (unsigned short)f2bf(v.x);
            *reinterpret_cast<unsigned short*>(&lds_w[fswz(wn4 + 1, kk * 2)]) = (unsigned short)f2bf(v.y);
            *reinterpret_cast<unsigned short*>(&lds_w[fswz(wn4 + 2, kk * 2)]) = (unsigned short)f2bf(v.z);
            *reinterpret_cast<unsigned short*>(&lds_w[fswz(wn4 + 3, kk * 2)]) = (unsigned short)f2bf(v.w);
        }
        __syncthreads();
        #pragma unroll
        for (int ks = 0; ks < 2; ++ks) {
            const int kb = ks * 64 + lg * 16;
            short8 a[4], b[4];
            #pragma unroll
            for (int mi = 0; mi < 4; ++mi)
                a[mi] = *reinterpret_cast<const short8*>(&lds_a[fswz(wm + mi * 16 + lr, kb)]);
            #pragma unroll
            for (int ni = 0; ni < 4; ++ni)
                b[ni] = *reinterpret_cast<const short8*>(&lds_w[fswz(wn + ni * 16 + lr, kb)]);
            #pragma unroll
            for (int mi = 0; mi < 4; ++mi)
                #pragma unroll
                for (int ni = 0; ni < 4; ++ni)
                    acc[mi][ni] = __builtin_amdgcn_mfma_f32_16x16x32_bf16(
                        a[mi], b[ni], acc[mi][ni], 0, 0, 0);
        }
        __syncthreads();
    }
    #pragma unroll
    for (int mi = 0; mi < 4; ++mi)
        #pragma unroll
        for (int ni = 0; ni < 4; ++ni)
            #pragma unroll
            for (int r = 0; r < 4; ++r) {
                const int row = bm + wm + mi * 16 + lg * 4 + r;
                const int col = bn + wn + ni * 16 + lr;
                out[(size_t)row * N_ + col] = acc[mi][ni][r];
            }
}

extern "C" void kernel_launch(void* const* d_in, const int* in_sizes, int n_in,
                              void* d_out, int out_size, void* d_ws, size_t ws_size,
                              hipStream_t stream) {
    const float* x = (const float*)d_in[0];
    const float* w = (const float*)d_in[1];
    float* out = (float*)d_out;

    const size_t need = ((size_t)MT * K_ + (size_t)K_ * N_) * sizeof(unsigned short); // 96 MB
    if (ws_size >= need) {
        unsigned short* xb = (unsigned short*)d_ws;            // [MT][K] bf16
        unsigned short* wt = xb + (size_t)MT * K_;             // [N][K]  bf16
        hipLaunchKernelGGL(cvt_x, dim3(4096), dim3(256), 0, stream, x, xb);
        hipLaunchKernelGGL(cvt_wt, dim3(K_ / TS, N_ / TS), dim3(256), 0, stream, w, wt);
        hipLaunchKernelGGL(gemm8, dim3((MT / 256) * (N_ / 256)), dim3(512), 0, stream,
                           xb, wt, out);
    } else {
        hipLaunchKernelGGL(ternary_gemm_fused, dim3(N_ / BN, MT / BM), dim3(256), 0,
                           stream, x, w, out);
    }
}

// Round 5
// 470.703 us; speedup vs baseline: 4.1171x; 1.0066x over previous
//
#include <hip/hip_runtime.h>
#include <hip/hip_bf16.h>
#include <stdint.h>

typedef __attribute__((ext_vector_type(8))) short short8;
typedef __attribute__((ext_vector_type(4))) float f32x4;

#define B_  4
#define M_  2048
#define K_  4096
#define N_  4096
#define MT  (B_ * M_)   // 8192 rows

// fp32 -> bf16 round-to-nearest-even (finite inputs)
__device__ __forceinline__ unsigned f2bf(float f) {
    unsigned u = __builtin_bit_cast(unsigned, f);
    return (u + 0x7fffu + ((u >> 16) & 1u)) >> 16;
}

__device__ __forceinline__ void gload16(const void* g, void* l) {
    __builtin_amdgcn_global_load_lds(
        (const __attribute__((address_space(1))) unsigned int*)g,
        (__attribute__((address_space(3))) unsigned int*)l,
        16 /*bytes, literal*/, 0, 0);
}

// ---------------- kernel 1: X fp32 -> bf16 (row-major) ---------------------
__global__ __launch_bounds__(256) void cvt_x(const float* __restrict__ x,
                                             unsigned short* __restrict__ xb) {
    const size_t n8 = (size_t)MT * K_ / 8;
    for (size_t i = (size_t)blockIdx.x * 256 + threadIdx.x; i < n8;
         i += (size_t)gridDim.x * 256) {
        const float4 v0 = reinterpret_cast<const float4*>(x)[i * 2 + 0];
        const float4 v1 = reinterpret_cast<const float4*>(x)[i * 2 + 1];
        uint4 p;
        p.x = f2bf(v0.x) | (f2bf(v0.y) << 16);
        p.y = f2bf(v0.z) | (f2bf(v0.w) << 16);
        p.z = f2bf(v1.x) | (f2bf(v1.y) << 16);
        p.w = f2bf(v1.z) | (f2bf(v1.w) << 16);
        reinterpret_cast<uint4*>(xb)[i] = p;
    }
}

// ---------------- kernel 2: W [K][N] fp32 -> Wt [N][K] bf16 ----------------
// Register 4x4 micro-transpose, no LDS (round-3 version had a 16-way LDS
// write conflict: bank = 40*n_loc mod 32 collapses 16 lanes to one bank).
// Reads: 64B-contiguous per 4-lane group; writes: 128B-contiguous per
// 16-lane group. Pure streaming.
#define TS 64
__global__ __launch_bounds__(256) void cvt_wt(const float* __restrict__ w,
                                              unsigned short* __restrict__ wt) {
    const int k0 = blockIdx.x * TS;
    const int n0 = blockIdx.y * TS;
    const int t  = threadIdx.x;
    const int kq = (t & 15) * 4;   // k offset of this thread's 4x4 block
    const int nq = (t >> 4) * 4;   // n offset

    float v[4][4];   // v[i][j] = W[k0+kq+i][n0+nq+j]
    #pragma unroll
    for (int i = 0; i < 4; ++i) {
        const float4 r = *reinterpret_cast<const float4*>(
            &w[(size_t)(k0 + kq + i) * N_ + n0 + nq]);
        v[i][0] = r.x; v[i][1] = r.y; v[i][2] = r.z; v[i][3] = r.w;
    }
    #pragma unroll
    for (int j = 0; j < 4; ++j) {
        uint2 p;
        p.x = f2bf(v[0][j]) | (f2bf(v[1][j]) << 16);
        p.y = f2bf(v[2][j]) | (f2bf(v[3][j]) << 16);
        *reinterpret_cast<uint2*>(&wt[(size_t)(n0 + nq + j) * K_ + k0 + kq]) = p;
    }
}

// ---------------- kernel 3: 256x256 8-phase bf16 MFMA GEMM -----------------
// Geometry: BM=BN=256, BK=64, 8 waves (2Mx4N), per-wave out 128x64.
// LDS 128 KiB: 2 dbuf x (A0,A1,B0,B1 half-tiles of 16 KB).
// Chunk swizzle (T2): within each 1 KB subtile (16 rows x 32 bf16),
// physical_chunk = logical_chunk ^ (((chunk>>5)&1)<<1)  [row-bit3 XOR chunk-bit1]
// applied on BOTH the global source (pre-swizzle) and the ds_read address.
#define BK    64
#define NTIL  (K_ / BK)   // 64 k-tiles
#define HALF  16384
#define BUFSZ 65536

__global__ __launch_bounds__(512, 2) void gemm8(
    const unsigned short* __restrict__ xb,   // [MT][K] bf16
    const unsigned short* __restrict__ wt,   // [N][K]  bf16
    float* __restrict__ out)
{
    __shared__ __align__(16) char lds[2 * BUFSZ];   // 128 KiB

    const int tid  = threadIdx.x;
    const int w    = tid >> 6;
    const int lane = tid & 63;
    const int lr   = lane & 15;
    const int lg   = lane >> 4;
    const int wm_idx = w >> 2;        // 0..1  (M)
    const int wn_idx = w & 3;         // 0..3  (N)

    // XCD-aware bijective swizzle (nwg=512, 512%8==0)
    const int bid = blockIdx.x;
    const int swz = (bid & 7) * 64 + (bid >> 3);
    const int bm  = (swz >> 4) * 256;
    const int bn  = (swz & 15) * 256;

    // ---- staging source precompute (write-side inverse swizzle) ----
    const int L   = w * 64 + lane;
    const int s0_ = L >> 6;
    const int cp  = L & 63;
    const int cl  = cp ^ (((cp >> 5) & 1) << 1);
    const int rst0 = (s0_ >> 1) * 16 + (cl >> 2);
    const int kst  = (s0_ & 1) * 32 + (cl & 3) * 8;
    const unsigned short* aS0 = xb + (size_t)(bm + rst0) * K_ + kst;
    const unsigned short* aS1 = xb + (size_t)(bm + rst0 + 64) * K_ + kst;
    const unsigned short* bS0 = wt + (size_t)(bn + rst0) * K_ + kst;
    const unsigned short* bS1 = wt + (size_t)(bn + rst0 + 64) * K_ + kst;
    char* const ldsw = lds + w * 1024;

    // ---- fragment read bases (read-side swizzle) ----
    const int laneoff = ((lr * 4 + lg) ^ (((lr >> 3) & 1) << 1)) * 16;
    const char* lpA = lds + wm_idx * HALF + laneoff;
    const char* lpB = lds + (2 + (wn_idx >> 1)) * HALF + (wn_idx & 1) * 8192 + laneoff;

    short8 af[4][2];
    short8 bf[4][2];
    f32x4  acc[8][4];
    #pragma unroll
    for (int i = 0; i < 8; ++i)
        #pragma unroll
        for (int j = 0; j < 4; ++j)
            acc[i][j] = f32x4{0.f, 0.f, 0.f, 0.f};

#define STAGE(ISB, HF, BUF, T) do {                                         \
        const size_t _k = (size_t)(((T) * BK) & (K_ - 1))                   \
                        + (size_t)(HF) * 128 * K_;                          \
        const unsigned short* _s0 = ((ISB) ? bS0 : aS0) + _k;               \
        const unsigned short* _s1 = ((ISB) ? bS1 : aS1) + _k;               \
        char* _l = ldsw + (BUF) * BUFSZ + ((ISB) * 2 + (HF)) * HALF;        \
        gload16(_s0, _l);                                                   \
        gload16(_s1, _l + 8192);                                            \
    } while (0)

#define LDA(H, BUF)                                                         \
    _Pragma("unroll") for (int m = 0; m < 4; ++m)                           \
    _Pragma("unroll") for (int ks = 0; ks < 2; ++ks)                        \
        af[m][ks] = *reinterpret_cast<const short8*>(                       \
            lpA + (BUF) * BUFSZ + (((H) * 4 + m) * 2 + ks) * 1024);

#define LDB(P, BUF)                                                         \
    _Pragma("unroll") for (int n = 0; n < 2; ++n)                           \
    _Pragma("unroll") for (int ks = 0; ks < 2; ++ks)                        \
        bf[(P) * 2 + n][ks] = *reinterpret_cast<const short8*>(             \
            lpB + (BUF) * BUFSZ + (((P) * 2 + n) * 2 + ks) * 1024);

#define MFMAQ(H, NLO)                                                       \
    __builtin_amdgcn_s_setprio(1);                                          \
    _Pragma("unroll") for (int m = 0; m < 4; ++m)                           \
    _Pragma("unroll") for (int n = 0; n < 2; ++n)                           \
    _Pragma("unroll") for (int ks = 0; ks < 2; ++ks)                        \
        acc[(H) * 4 + m][(NLO) + n] = __builtin_amdgcn_mfma_f32_16x16x32_bf16( \
            af[m][ks], bf[(NLO) + n][ks], acc[(H) * 4 + m][(NLO) + n], 0, 0, 0); \
    __builtin_amdgcn_s_setprio(0);

#define BAR() __builtin_amdgcn_s_barrier()

    // ---- prologue: tile0 (all 4 halves) -> buf0; tile1 A0,A1 -> buf1 ----
    STAGE(0, 0, 0, 0); STAGE(0, 1, 0, 0);
    STAGE(1, 0, 0, 0); STAGE(1, 1, 0, 0);
    STAGE(0, 0, 1, 1); STAGE(0, 1, 1, 1);
    asm volatile("s_waitcnt vmcnt(4)" ::: "memory");
    BAR();

    // ---- main loop: 8 phases per iter, 2 k-tiles per iter ----
#define HALFITER(BUF, TB, TA)                                               \
    /* q0 */ LDA(0, BUF); LDB(0, BUF);                                      \
    STAGE(1, 0, (BUF) ^ 1, TB);                                             \
    BAR(); MFMAQ(0, 0); BAR();                                              \
    /* q1 */ LDB(1, BUF);                                                   \
    STAGE(1, 1, (BUF) ^ 1, TB);                                             \
    BAR(); MFMAQ(0, 2); BAR();                                              \
    /* q2 */ LDA(1, BUF);                                                   \
    STAGE(0, 0, BUF, TA);                                                   \
    BAR(); MFMAQ(1, 0); BAR();                                              \
    /* q3 */ STAGE(0, 1, BUF, TA);                                          \
    asm volatile("s_waitcnt vmcnt(4)" ::: "memory");                        \
    BAR(); MFMAQ(1, 2); BAR();

    for (int i = 0; i < NTIL / 2; ++i) {
        const int T = 2 * i;
        HALFITER(0, T + 1, T + 2)
        HALFITER(1, T + 2, T + 3)
    }

    // ---- epilogue: C/D layout col=lane&15, row=(lane>>4)*4+r ----
    #pragma unroll
    for (int m = 0; m < 8; ++m)
        #pragma unroll
        for (int n = 0; n < 4; ++n)
            #pragma unroll
            for (int r = 0; r < 4; ++r) {
                const int row = bm + wm_idx * 128 + m * 16 + lg * 4 + r;
                const int col = bn + wn_idx * 64 + n * 16 + lr;
                out[(size_t)row * N_ + col] = acc[m][n][r];
            }
#undef STAGE
#undef LDA
#undef LDB
#undef MFMAQ
#undef BAR
#undef HALFITER
}

// ---------------- fallback: round-2 fused kernel (passes, 1.8 ms) ----------
#define BM  128
#define BN  128
#define FLDSB (BK * 2)
__device__ __forceinline__ int fswz(int row, int kbyte) {
    return row * FLDSB + (kbyte ^ ((row & 7) << 4));
}
__global__ __launch_bounds__(256) void ternary_gemm_fused(
    const float* __restrict__ x, const float* __restrict__ w,
    float* __restrict__ out)
{
    __shared__ __align__(16) char lds_a[BM * FLDSB];
    __shared__ __align__(16) char lds_w[BN * FLDSB];
    const int tid = threadIdx.x;
    const int bn = blockIdx.x * BN, bm = blockIdx.y * BM;
    const int wave = tid >> 6, lane = tid & 63;
    const int lr = lane & 15, lg = lane >> 4;
    const int wm = (wave >> 1) * 64, wn = (wave & 1) * 64;
    f32x4 acc[4][4];
    #pragma unroll
    for (int i = 0; i < 4; ++i)
        #pragma unroll
        for (int j = 0; j < 4; ++j) acc[i][j] = f32x4{0.f, 0.f, 0.f, 0.f};
    const int ar = tid >> 4, ak = (tid & 15) * 4;
    const int wk = tid >> 5, wn4 = (tid & 31) * 4;
    for (int k0 = 0; k0 < K_; k0 += BK) {
        #pragma unroll
        for (int it = 0; it < 8; ++it) {
            const int row = ar + it * 16;
            const float4 v = *reinterpret_cast<const float4*>(
                &x[(size_t)(bm + row) * K_ + k0 + ak]);
            uint2 p;
            p.x = f2bf(v.x) | (f2bf(v.y) << 16);
            p.y = f2bf(v.z) | (f2bf(v.w) << 16);
            *reinterpret_cast<uint2*>(&lds_a[fswz(row, ak * 2)]) = p;
        }
        #pragma unroll
        for (int it = 0; it < 8; ++it) {
            const int kk = wk + it * 8;
            const float4 v = *reinterpret_cast<const float4*>(
                &w[(size_t)(k0 + kk) * N_ + bn + wn4]);
            *reinterpret_cast<unsigned short*>(&lds_w[fswz(wn4 + 0, kk * 2)]) = (unsigned short)f2bf(v.x);
            *reinterpret_cast<unsigned short*>(&lds_w[fswz(wn4 + 1, kk * 2)]) = (unsigned short)f2bf(v.y);
            *reinterpret_cast<unsigned short*>(&lds_w[fswz(wn4 + 2, kk * 2)]) = (unsigned short)f2bf(v.z);
            *reinterpret_cast<unsigned short*>(&lds_w[fswz(wn4 + 3, kk * 2)]) = (unsigned short)f2bf(v.w);
        }
        __syncthreads();
        #pragma unroll
        for (int ks = 0; ks < 2; ++ks) {
            const int kb = ks * 64 + lg * 16;
            short8 a[4], b[4];
            #pragma unroll
            for (int mi = 0; mi < 4; ++mi)
                a[mi] = *reinterpret_cast<const short8*>(&lds_a[fswz(wm + mi * 16 + lr, kb)]);
            #pragma unroll
            for (int ni = 0; ni < 4; ++ni)
                b[ni] = *reinterpret_cast<const short8*>(&lds_w[fswz(wn + ni * 16 + lr, kb)]);
            #pragma unroll
            for (int mi = 0; mi < 4; ++mi)
                #pragma unroll
                for (int ni = 0; ni < 4; ++ni)
                    acc[mi][ni] = __builtin_amdgcn_mfma_f32_16x16x32_bf16(
                        a[mi], b[ni], acc[mi][ni], 0, 0, 0);
        }
        __syncthreads();
    }
    #pragma unroll
    for (int mi = 0; mi < 4; ++mi)
        #pragma unroll
        for (int ni = 0; ni < 4; ++ni)
            #pragma unroll
            for (int r = 0; r < 4; ++r) {
                const int row = bm + wm + mi * 16 + lg * 4 + r;
                const int col = bn + wn + ni * 16 + lr;
                out[(size_t)row * N_ + col] = acc[mi][ni][r];
            }
}

extern "C" void kernel_launch(void* const* d_in, const int* in_sizes, int n_in,
                              void* d_out, int out_size, void* d_ws, size_t ws_size,
                              hipStream_t stream) {
    const float* x = (const float*)d_in[0];
    const float* w = (const float*)d_in[1];
    float* out = (float*)d_out;

    const size_t need = ((size_t)MT * K_ + (size_t)K_ * N_) * sizeof(unsigned short); // 96 MB
    if (ws_size >= need) {
        unsigned short* xb = (unsigned short*)d_ws;            // [MT][K] bf16
        unsigned short* wt = xb + (size_t)MT * K_;             // [N][K]  bf16
        hipLaunchKernelGGL(cvt_x, dim3(4096), dim3(256), 0, stream, x, xb);
        hipLaunchKernelGGL(cvt_wt, dim3(K_ / TS, N_ / TS), dim3(256), 0, stream, w, wt);
        hipLaunchKernelGGL(gemm8, dim3((MT / 256) * (N_ / 256)), dim3(512), 0, stream,
                           xb, wt, out);
    } else {
        hipLaunchKernelGGL(ternary_gemm_fused, dim3(N_ / BN, MT / BM), dim3(256), 0,
                           stream, x, w, out);
    }
}